// Round 16
// baseline (255.091 us; speedup 1.0000x reference)
//
#include <hip/hip_runtime.h>
#include <cstddef>

#define NN 50000
#define NREL 3
#define NE 250000
#define NP 100000
#define FIN 128
#define HD 256
#define SLOPE 0.2f
#define K1 (NREL * FIN)          // 384

typedef short bf16x8 __attribute__((ext_vector_type(8)));
typedef short bf16x2 __attribute__((ext_vector_type(2)));
typedef float f32x4 __attribute__((ext_vector_type(4)));
typedef _Float16 half8 __attribute__((ext_vector_type(8)));

__device__ __forceinline__ short f2bf(float f) {
  unsigned u = __float_as_uint(f);
  unsigned r = (u + 0x7FFFu + ((u >> 16) & 1u)) >> 16;   // RNE
  return (short)r;
}
__device__ __forceinline__ float bf2f(short s) {
  return __uint_as_float(((unsigned)(unsigned short)s) << 16);
}

// async global->LDS, 16 bytes per lane; lds ptr must be wave-uniform base.
__device__ __forceinline__ void gload16(const short* g, short* l) {
  __builtin_amdgcn_global_load_lds(
      (const __attribute__((address_space(1))) unsigned int*)g,
      (__attribute__((address_space(3))) unsigned int*)l, 16, 0, 0);
}

// -------- fused prep + edge counting (rank capture) -----------------------
// ranges: [0,2930) count+rank | [2930,9180) xconv | [9180,9564) W1d f16
//         [9564,9948) W2t | [9948,10140) wvec1 | [10140,10142) beff
// swizzle: element (n,k) stored at k ^ ((n&7)<<3)  [within 64-short windows]
__global__ __launch_bounds__(256) void prep_all(
    const float* __restrict__ x,  const float* __restrict__ W1,
    const float* __restrict__ W2, const float* __restrict__ al1,
    const float* __restrict__ ar1, const float* __restrict__ b1,
    const float* __restrict__ b2,  const int* __restrict__ edges,
    int* __restrict__ deg, int* __restrict__ rank,
    short* __restrict__ xb, short* __restrict__ W1d, short* __restrict__ W2t,
    float* __restrict__ wvec1, float* __restrict__ beff1, float* __restrict__ beff2)
{
  const int blk = blockIdx.x;
  const int t = threadIdx.x;
  if (blk < 2930) {                                   // edge count + rank
    int tid2 = blk * 256 + t;
    if (tid2 < NREL * NE) {
      int r = tid2 / NE;
      int e = tid2 - r * NE;
      int d = edges[(size_t)r * 2 * NE + NE + e];
      rank[tid2] = atomicAdd(&deg[r * NN + d], 1);
    }
  } else if (blk < 9180) {                            // x -> bf16
    int i = ((blk - 2930) * 256 + t) * 4;
    float4 v = *(const float4*)&x[i];
    short4 o = {f2bf(v.x), f2bf(v.y), f2bf(v.z), f2bf(v.w)};
    *(short4*)&xb[i] = o;
  } else if (blk < 9564) {                            // W1d[n][kpos] f16, k<384
    int o = (blk - 9180) * 256 + t;
    int n = o / K1;
    int kpos = o - n * K1;
    int ke = kpos ^ ((n & 7) << 3);                   // element for this slot
    int r = ke / FIN, kk = ke - r * FIN;
    ((_Float16*)W1d)[o] = (_Float16)W1[((size_t)r * FIN + kk) * HD + n];
  } else if (blk < 9948) {                            // W2t[r][n][kpos] bf16
    int o = (blk - 9564) * 256 + t;
    int r = o / (FIN * HD);
    int rem = o - r * (FIN * HD);
    int n = rem / HD, kpos = rem - n * HD;
    int ke = kpos ^ ((n & 7) << 3);
    W2t[o] = f2bf(W2[((size_t)r * HD + ke) * FIN + n]);
  } else if (blk < 10140) {                           // wvec1[j][k] = W1_r[k,:]·v
    int wid = (blk - 9948) * 4 + (t >> 6);
    int lane = t & 63;
    if (wid < 6 * FIN) {
      int j = wid / FIN, k = wid - j * FIN;
      int side = j / 3, r = j - side * 3;
      const float* v  = (side ? ar1 : al1) + r * HD;
      const float* Wr = W1 + ((size_t)r * FIN + k) * HD;
      float s = 0.f;
      for (int n = lane; n < HD; n += 64) s += Wr[n] * v[n];
#pragma unroll
      for (int off = 32; off > 0; off >>= 1) s += __shfl_down(s, off);
      if (lane == 0) wvec1[wid] = s;
    }
  } else {                                            // beff
    int t2 = (blk - 10140) * 256 + t;
    if (t2 < HD) beff1[t2] = (b1[t2] + b1[HD + t2] + b1[2 * HD + t2]) * (1.f / 3.f);
    else if (t2 < HD + FIN) {
      int k = t2 - HD;
      beff2[k] = (b2[k] + b2[FIN + k] + b2[2 * FIN + k]) * (1.f / 3.f);
    }
  }
}

// ------- el/er for layer 1: d[j] = xb[i,:]·wvec1[j,:], j<6 ----------------
__global__ __launch_bounds__(256) void rowdot6(
    const short* __restrict__ feat, const float* __restrict__ wvec,
    float* __restrict__ el, float* __restrict__ er)
{
  const int lane = threadIdx.x & 63;
  const int node = blockIdx.x * 4 + (threadIdx.x >> 6);
  if (node >= NN) return;
  bf16x2 f16 = *(const bf16x2*)&feat[(size_t)node * FIN + lane * 2];
  float f0 = bf2f(f16[0]), f1 = bf2f(f16[1]);
  float d[6];
#pragma unroll
  for (int j = 0; j < 6; ++j)
    d[j] = f0 * wvec[j * FIN + lane * 2] + f1 * wvec[j * FIN + lane * 2 + 1];
#pragma unroll
  for (int off = 32; off > 0; off >>= 1)
#pragma unroll
    for (int j = 0; j < 6; ++j) d[j] += __shfl_xor(d[j], off);
  if (lane == 0) {
    el[0 * NN + node] = d[0]; el[1 * NN + node] = d[1]; el[2 * NN + node] = d[2];
    er[0 * NN + node] = d[3]; er[1 * NN + node] = d[4]; er[2 * NN + node] = d[5];
  }
}

// ------------- CSR scan phase 1 -------------------------------------------
__global__ __launch_bounds__(256) void deg_partial(
    const int* __restrict__ deg, int* __restrict__ psum)
{
  const int b = blockIdx.x;
  const int t = threadIdx.x;
  int4 v = {0, 0, 0, 0};
  if (t < 250) v = *(const int4*)&deg[b * 1000 + t * 4];
  int s = v.x + v.y + v.z + v.w;
#pragma unroll
  for (int off = 32; off > 0; off >>= 1) s += __shfl_down(s, off);
  __shared__ int ws[4];
  if ((t & 63) == 0) ws[t >> 6] = s;
  __syncthreads();
  if (t == 0) psum[b] = ws[0] + ws[1] + ws[2] + ws[3];
}

// ------------- CSR scan phase 2 -------------------------------------------
__global__ __launch_bounds__(256) void scan_psum(
    const int* __restrict__ psum, int* __restrict__ pexcl)
{
  __shared__ int lds[256];
  const int t = threadIdx.x;
  int v = (t < 150) ? psum[t] : 0;
  lds[t] = v;
  __syncthreads();
  for (int off = 1; off < 256; off <<= 1) {
    int add = (t >= off) ? lds[t - off] : 0;
    __syncthreads();
    lds[t] += add;
    __syncthreads();
  }
  if (t < 150) pexcl[t] = lds[t] - v;
}

// ------------- CSR scan phase 3: row_ptr --------------------------------
__global__ __launch_bounds__(256) void deg_rowptr(
    const int* __restrict__ deg, const int* __restrict__ pexcl,
    int* __restrict__ row_ptr)
{
  const int b = blockIdx.x;
  const int t = threadIdx.x;
  int4 v = {0, 0, 0, 0};
  if (t < 250) v = *(const int4*)&deg[b * 1000 + t * 4];
  int s = v.x + v.y + v.z + v.w;
  __shared__ int lds[256];
  lds[t] = s;
  __syncthreads();
  for (int off = 1; off < 256; off <<= 1) {
    int add = (t >= off) ? lds[t - off] : 0;
    __syncthreads();
    lds[t] += add;
    __syncthreads();
  }
  int run = lds[t] - s + pexcl[b];
  if (t < 250) {
    int i = b * 1000 + t * 4;
    row_ptr[i] = run;     run += v.x;
    row_ptr[i + 1] = run; run += v.y;
    row_ptr[i + 2] = run; run += v.z;
    row_ptr[i + 3] = run;
  }
  if (b == 0 && t == 0) row_ptr[NREL * NN] = NREL * NE;
}

// ------------- CSR fill: atomic-free (uses captured rank) -----------------
__global__ __launch_bounds__(256) void fill_csr(
    const int* __restrict__ edges, const int* __restrict__ row_ptr,
    const int* __restrict__ rank, int* __restrict__ csr_src)
{
  int tid = blockIdx.x * blockDim.x + threadIdx.x;
  if (tid >= NREL * NE) return;
  int r = tid / NE;
  int e = tid - r * NE;
  const int* base = edges + (size_t)r * 2 * NE;
  int s = base[e];
  int d = base[NE + e];
  csr_src[row_ptr[r * NN + d] + rank[tid]] = s;
}

// ------------- canonicalize bucket order: sort each bucket by src ---------
// Makes csr_src a pure function of the inputs (atomic arrival order erased)
// -> every kernel_launch call is bit-identical. One thread per bucket.
__global__ __launch_bounds__(256) void sort_csr(
    const int* __restrict__ row_ptr, int* __restrict__ csr_src)
{
  int b = blockIdx.x * 256 + threadIdx.x;
  if (b >= NREL * NN) return;
  const int beg = row_ptr[b];
  const int end = row_ptr[b + 1];
  const int n = end - beg;
  if (n <= 1) return;
  if (n <= 24) {                         // deg ~ Poisson(5): covers ~1-3e-10
    int v[24];
    for (int i = 0; i < n; ++i) v[i] = csr_src[beg + i];
    for (int i = 1; i < n; ++i) {
      int key = v[i];
      int j = i - 1;
      while (j >= 0 && v[j] > key) { v[j + 1] = v[j]; --j; }
      v[j + 1] = key;
    }
    for (int i = 0; i < n; ++i) csr_src[beg + i] = v[i];
  } else {                               // rare: deterministic in-place
    for (int i = beg; i < end - 1; ++i) {
      int mi = i;
      for (int j = i + 1; j < end; ++j)
        if (csr_src[j] < csr_src[mi]) mi = j;
      int tmp = csr_src[mi]; csr_src[mi] = csr_src[i]; csr_src[i] = tmp;
    }
  }
}

// ------- L1: input-space fused 3-relation gather, 16 lanes per node -------
// 4 nodes/wave; each lane owns 8 channels. A1 written as fp16, PRE-SWIZZLED:
// element (node,k) at k ^ ((node&7)<<3).
__global__ __launch_bounds__(256) void gat_gather_hl(
    const int* __restrict__ row_ptr, const int* __restrict__ csr_src,
    const float* __restrict__ el, const float* __restrict__ er,
    const short* __restrict__ xb,       // [NN][FIN] bf16
    short* __restrict__ A1)             // [NN][384] f16, swizzled
{
  const int lane  = threadIdx.x & 63;
  const int cl    = lane & 15;
  const int gbase = lane & 48;
  const int node  = blockIdx.x * 16 + (threadIdx.x >> 6) * 4 + (lane >> 4);
  if (node >= NN) return;
  const int sw = (node & 7) << 3;
  const size_t rowbase = (size_t)node * K1;

#pragma unroll
  for (int r = 0; r < NREL; ++r) {
    const int beg = row_ptr[r * NN + node];
    const int end = row_ptr[r * NN + node + 1];
    const float eri = er[r * NN + node];
    const float* elr = el + r * NN;

    float dsum = 0.f;
    float f[8];
#pragma unroll
    for (int k = 0; k < 8; ++k) f[k] = 0.f;

    for (int chunk = beg; chunk < end; chunk += 16) {
      int e = chunk + cl;
      int sidx = 0; float a = 0.f;
      if (e < end) {
        sidx = csr_src[e];
        float tv = elr[sidx] + eri;
        tv = tv > 0.f ? tv : SLOPE * tv;
        a = __expf(tv);
      }
      dsum += a;
      const int cnt = (end - chunk < 16) ? end - chunk : 16;
      for (int i = 0; i < cnt; ++i) {
        float aj = __shfl(a, gbase + i);
        int   sj = __shfl(sidx, gbase + i);
        bf16x8 v = *(const bf16x8*)&xb[(size_t)sj * FIN + cl * 8];
#pragma unroll
        for (int k = 0; k < 8; ++k) f[k] = fmaf(bf2f(v[k]), aj, f[k]);
      }
    }
#pragma unroll
    for (int off = 8; off > 0; off >>= 1) dsum += __shfl_xor(dsum, off);
    const float inv = 1.f / (3.f * fmaxf(dsum, 1e-9f));

    half8 hv;
#pragma unroll
    for (int k = 0; k < 8; ++k) hv[k] = (_Float16)(f[k] * inv);
    int u = (r * FIN + cl * 8) ^ sw;       // swizzled within 64-short window
    *(half8*)&A1[rowbase + u] = hv;
  }
}

// ------- L1 GEMM: hb = relu(A1@W1d^T + beff1), f16 MFMA, A read ONCE ------
// BM=64, BN=256 (full width, wave=64 cols), BK=64, K=384. LDS 40 KB.
__global__ __launch_bounds__(256) void gemm_hl(
    const short* __restrict__ A, const short* __restrict__ Bt,
    const float* __restrict__ beff, short* __restrict__ hb, int M)
{
  constexpr int BK = 64;
  __shared__ __align__(16) short AsB[(64 + 256) * BK];  // 40 KB
  short* As = AsB;
  short* Bs = AsB + 64 * BK;
  const int tid  = threadIdx.x;
  const int lane = tid & 63;
  const int wave = tid >> 6;
  const int m0 = blockIdx.x * 64;
  const int n0 = wave * 64;
  const int c    = lane & 15;
  const int rgrp = lane >> 4;
  const int wbase = tid & ~63;         // wave-uniform chunk base

  f32x4 acc[4][4] = {};
  for (int k0 = 0; k0 < K1; k0 += BK) {
    __syncthreads();
#pragma unroll
    for (int q = 0; q < 2; ++q) {      // A: 512 chunks
      int idx = q * 256 + tid;
      int row = idx >> 3, ch = idx & 7;
      int gr = m0 + row; gr = gr < M ? gr : M - 1;
      gload16(&A[(size_t)gr * K1 + k0 + ch * 8], As + (q * 256 + wbase) * 8);
    }
#pragma unroll
    for (int q = 0; q < 8; ++q) {      // B: 2048 chunks (256 cols)
      int jdx = q * 256 + tid;
      int col = jdx >> 3, ch = jdx & 7;
      gload16(&Bt[(size_t)col * K1 + k0 + ch * 8], Bs + (q * 256 + wbase) * 8);
    }
    __syncthreads();
#pragma unroll
    for (int ks = 0; ks < 2; ++ks) {
      const int ko = (ks * 32 + rgrp * 8) ^ ((c & 7) << 3);  // de-swizzle
      half8 a[4], b[4];
#pragma unroll
      for (int i = 0; i < 4; ++i)
        a[i] = *(const half8*)&As[(i * 16 + c) * BK + ko];
#pragma unroll
      for (int j = 0; j < 4; ++j)
        b[j] = *(const half8*)&Bs[(n0 + j * 16 + c) * BK + ko];
#pragma unroll
      for (int i = 0; i < 4; ++i)
#pragma unroll
        for (int j = 0; j < 4; ++j)
          acc[i][j] = __builtin_amdgcn_mfma_f32_16x16x32_f16(a[i], b[j], acc[i][j], 0, 0, 0);
    }
  }
#pragma unroll
  for (int i = 0; i < 4; ++i)
#pragma unroll
    for (int v = 0; v < 4; ++v) {
      int row = m0 + i * 16 + rgrp * 4 + v;
      if (row < M) {
        int srow = (row & 7) << 3;
#pragma unroll
        for (int j = 0; j < 4; ++j) {
          int col = n0 + j * 16 + c;
          hb[(size_t)row * HD + (col ^ srow)] =
              f2bf(fmaxf(acc[i][j][v] + beff[col], 0.f));
        }
      }
    }
}

// ---- L2 GEMM: featb[r] = hb @ W2t[r]^T + el/er epilogue (bf16 MFMA) ------
// BM=64, BN=128 (full N), BK=64, grid y=3. hb/W2t are pre-swizzled.
__global__ __launch_bounds__(256) void gemm_fused2(
    const short* __restrict__ A, const short* __restrict__ Wt,
    const float* __restrict__ al, const float* __restrict__ ar,
    short* __restrict__ featb, float* __restrict__ el, float* __restrict__ er,
    int M)
{
  constexpr int K = HD;                // 256
  constexpr int BK = 64;
  constexpr int N_ = FIN;              // 128
  __shared__ __align__(16) short AsB[(64 + 128) * BK];  // 24 KB
  __shared__ float2 part[4][64];
  short* As = AsB;
  short* Bs = AsB + 64 * BK;
  const int r = blockIdx.y;
  const short* Bt  = Wt + (size_t)r * N_ * K;
  const float* alr = al + r * N_;
  const float* arr = ar + r * N_;
  short* fb  = featb + (size_t)r * M * N_;
  float* elr = el + r * NN;
  float* err = er + r * NN;

  const int tid  = threadIdx.x;
  const int lane = tid & 63;
  const int wave = tid >> 6;
  const int m0 = blockIdx.x * 64;
  const int c    = lane & 15;
  const int rgrp = lane >> 4;
  const int wbase = tid & ~63;

  f32x4 acc[4][2] = {};
  for (int k0 = 0; k0 < K; k0 += BK) {
    __syncthreads();
#pragma unroll
    for (int q = 0; q < 2; ++q) {
      int idx = q * 256 + tid;
      int row = idx >> 3, ch = idx & 7;
      int gr = m0 + row; gr = gr < M ? gr : M - 1;
      gload16(&A[(size_t)gr * K + k0 + ch * 8], As + (q * 256 + wbase) * 8);
    }
#pragma unroll
    for (int q = 0; q < 4; ++q) {
      int jdx = q * 256 + tid;
      int col = jdx >> 3, ch = jdx & 7;
      gload16(&Bt[(size_t)col * K + k0 + ch * 8], Bs + (q * 256 + wbase) * 8);
    }
    __syncthreads();
#pragma unroll
    for (int ks = 0; ks < 2; ++ks) {
      const int ko = (ks * 32 + rgrp * 8) ^ ((c & 7) << 3);
      bf16x8 a[4], b[2];
#pragma unroll
      for (int i = 0; i < 4; ++i)
        a[i] = *(const bf16x8*)&As[(i * 16 + c) * BK + ko];
#pragma unroll
      for (int j = 0; j < 2; ++j)
        b[j] = *(const bf16x8*)&Bs[(wave * 32 + j * 16 + c) * BK + ko];
#pragma unroll
      for (int i = 0; i < 4; ++i)
#pragma unroll
        for (int j = 0; j < 2; ++j)
          acc[i][j] = __builtin_amdgcn_mfma_f32_16x16x32_bf16(a[i], b[j], acc[i][j], 0, 0, 0);
    }
  }

  // epilogue: featb (bf16, normal layout) + el/er dots
  float pe[4][4], pr[4][4];
#pragma unroll
  for (int i = 0; i < 4; ++i)
#pragma unroll
    for (int v = 0; v < 4; ++v) {
      float se = 0.f, sr = 0.f;
#pragma unroll
      for (int j = 0; j < 2; ++j) {
        float av = acc[i][j][v];
        int col = wave * 32 + j * 16 + c;
        se = fmaf(av, alr[col], se);
        sr = fmaf(av, arr[col], sr);
      }
      pe[i][v] = se; pr[i][v] = sr;
    }
#pragma unroll
  for (int i = 0; i < 4; ++i)
#pragma unroll
    for (int v = 0; v < 4; ++v) {
      int row = m0 + i * 16 + rgrp * 4 + v;
      if (row < M) {
#pragma unroll
        for (int j = 0; j < 2; ++j)
          fb[(size_t)row * N_ + wave * 32 + j * 16 + c] = f2bf(acc[i][j][v]);
      }
#pragma unroll
      for (int off = 1; off < 16; off <<= 1) {
        pe[i][v] += __shfl_xor(pe[i][v], off);
        pr[i][v] += __shfl_xor(pr[i][v], off);
      }
    }
  if (c == 0) {
#pragma unroll
    for (int i = 0; i < 4; ++i)
#pragma unroll
      for (int v = 0; v < 4; ++v)
        part[wave][i * 16 + rgrp * 4 + v] = make_float2(pe[i][v], pr[i][v]);
  }
  __syncthreads();
  if (tid < 64) {
    float se = 0.f, sr = 0.f;
#pragma unroll
    for (int w = 0; w < 4; ++w) { se += part[w][tid].x; sr += part[w][tid].y; }
    int row = m0 + tid;
    if (row < M) { elr[row] = se; err[row] = sr; }
  }
}

// ---- L2: projected-space gather + relu + predictor dots, 16 lanes/node ---
__global__ __launch_bounds__(256) void gat_agg_dots(
    const int* __restrict__ row_ptr, const int* __restrict__ csr_src,
    const float* __restrict__ el, const float* __restrict__ er,
    const short* __restrict__ featb,    // [NREL][NN][FIN] bf16 (normal layout)
    const float* __restrict__ beff,     // [FIN]
    const float* __restrict__ Wlin,     // [2*FIN]
    float* __restrict__ dotl, float* __restrict__ dotr)
{
  const int lane  = threadIdx.x & 63;
  const int cl    = lane & 15;
  const int gbase = lane & 48;
  const int node  = blockIdx.x * 16 + (threadIdx.x >> 6) * 4 + (lane >> 4);
  if (node >= NN) return;

  float t[8];
#pragma unroll
  for (int k = 0; k < 8; ++k) t[k] = 0.f;

#pragma unroll
  for (int r = 0; r < NREL; ++r) {
    const int beg = row_ptr[r * NN + node];
    const int end = row_ptr[r * NN + node + 1];
    const float eri = er[r * NN + node];
    const float* elr = el + r * NN;
    const short* fb  = featb + (size_t)r * NN * FIN;

    float dsum = 0.f;
    float f[8];
#pragma unroll
    for (int k = 0; k < 8; ++k) f[k] = 0.f;

    for (int chunk = beg; chunk < end; chunk += 16) {
      int e = chunk + cl;
      int sidx = 0; float a = 0.f;
      if (e < end) {
        sidx = csr_src[e];
        float tv = elr[sidx] + eri;
        tv = tv > 0.f ? tv : SLOPE * tv;
        a = __expf(tv);
      }
      dsum += a;
      const int cnt = (end - chunk < 16) ? end - chunk : 16;
      for (int i = 0; i < cnt; ++i) {
        float aj = __shfl(a, gbase + i);
        int   sj = __shfl(sidx, gbase + i);
        bf16x8 v = *(const bf16x8*)&fb[(size_t)sj * FIN + cl * 8];
#pragma unroll
        for (int k = 0; k < 8; ++k) f[k] = fmaf(bf2f(v[k]), aj, f[k]);
      }
    }
#pragma unroll
    for (int off = 8; off > 0; off >>= 1) dsum += __shfl_xor(dsum, off);
    const float inv = 1.f / (3.f * fmaxf(dsum, 1e-9f));
#pragma unroll
    for (int k = 0; k < 8; ++k) t[k] = fmaf(f[k], inv, t[k]);
  }

  const int c = cl * 8;
  float dl = 0.f, dr = 0.f;
#pragma unroll
  for (int k = 0; k < 8; ++k) {
    float g = fmaxf(t[k] + beff[c + k], 0.f);
    dl = fmaf(g, Wlin[c + k], dl);
    dr = fmaf(g, Wlin[FIN + c + k], dr);
  }
#pragma unroll
  for (int off = 8; off > 0; off >>= 1) {
    dl += __shfl_xor(dl, off);
    dr += __shfl_xor(dr, off);
  }
  if (cl == 0) { dotl[node] = dl; dotr[node] = dr; }
}

// ------------- pair logits -------------------------------------------------
__global__ __launch_bounds__(256) void pair_out(
    const int* __restrict__ edges, const int* __restrict__ n_pairs,
    const float* __restrict__ dotl, const float* __restrict__ dotr,
    const float* __restrict__ blin, float* __restrict__ out)
{
  const int TOT = NREL * NE + NP;
  int p = blockIdx.x * blockDim.x + threadIdx.x;
  if (p >= TOT) return;
  int s, d;
  if (p < NREL * NE) {
    int r = p / NE;
    int e = p - r * NE;
    const int* base = edges + (size_t)r * 2 * NE;
    s = base[e];
    d = base[NE + e];
  } else {
    int q = p - NREL * NE;
    s = n_pairs[2 * q];
    d = n_pairs[2 * q + 1];
  }
  float logit = dotl[s] + dotr[d] + blin[0];
  out[p] = 1.f / (1.f + expf(-logit));
}

extern "C" void kernel_launch(void* const* d_in, const int* in_sizes, int n_in,
                              void* d_out, int out_size, void* d_ws, size_t ws_size,
                              hipStream_t stream) {
  const float* x      = (const float*)d_in[0];
  const int*   edges  = (const int*)d_in[1];
  const int*   npairs = (const int*)d_in[2];
  const float* W1     = (const float*)d_in[3];
  const float* al1    = (const float*)d_in[4];
  const float* ar1    = (const float*)d_in[5];
  const float* b1     = (const float*)d_in[6];
  const float* W2     = (const float*)d_in[7];
  const float* al2    = (const float*)d_in[8];
  const float* ar2    = (const float*)d_in[9];
  const float* b2     = (const float*)d_in[10];
  const float* Wlin   = (const float*)d_in[11];
  const float* blin   = (const float*)d_in[12];
  float* out = (float*)d_out;

  char* w = (char*)d_ws;
  size_t off = 0;
  auto alloc = [&](size_t bytes) {
    char* p = w + off;
    off = (off + bytes + 255) & ~(size_t)255;
    return p;
  };
  short* xb      = (short*)alloc((size_t)NN * FIN * 2);     // 12.8 MB
  short* hb      = (short*)alloc((size_t)NN * HD * 2);      // 25.6 MB
  short* A1      = (short*)alloc((size_t)NN * K1 * 2);      // 38.4 MB (f16)
  short* featb2  = A1;   // aliased: A1 dead after gemm_hl (needs 38.4 MB)
  short* W1d     = (short*)alloc((size_t)HD * K1 * 2);      // 196 KB (f16)
  short* W2t     = (short*)alloc((size_t)NREL * FIN * HD * 2);
  float* wvec1   = (float*)alloc(6 * FIN * 4);
  float* beff1   = (float*)alloc(HD * 4);
  float* beff2   = (float*)alloc(FIN * 4);
  float* el      = (float*)alloc((size_t)NREL * NN * 4);
  float* er      = (float*)alloc((size_t)NREL * NN * 4);
  float* dotl    = (float*)alloc((size_t)NN * 4);
  float* dotr    = (float*)alloc((size_t)NN * 4);
  int*   deg     = (int*)  alloc((size_t)NREL * NN * 4);
  int*   rank    = (int*)  alloc((size_t)NREL * NE * 4);    // 3 MB
  int*   row_ptr = (int*)  alloc((size_t)(NREL * NN + 16) * 4);
  int*   psum    = (int*)  alloc(1024);
  int*   pexcl   = (int*)  alloc(1024);
  int*   csr_src = (int*)  alloc((size_t)NREL * NE * 4);

  const int B = 256;

  // ---------------- prep + edge count (1 kernel) --------------------------
  hipMemsetAsync(deg, 0, (size_t)NREL * NN * 4, stream);
  prep_all<<<10142, B, 0, stream>>>(x, W1, W2, al1, ar1, b1, b2, edges,
                                    deg, rank, xb, W1d, W2t, wvec1, beff1, beff2);

  // ---------------- CSR scan + atomic-free fill + canonical sort ----------
  deg_partial<<<150, B, 0, stream>>>(deg, psum);
  scan_psum<<<1, B, 0, stream>>>(psum, pexcl);
  deg_rowptr<<<150, B, 0, stream>>>(deg, pexcl, row_ptr);
  fill_csr<<<(NREL * NE + B - 1) / B, B, 0, stream>>>(edges, row_ptr, rank, csr_src);
  sort_csr<<<(NREL * NN + B - 1) / B, B, 0, stream>>>(row_ptr, csr_src);

  const int AGG_G  = (NN + 3) / 4;
  const int AGG16  = (NN + 15) / 16;    // 3125
  const int GEMM_GX = (NN + 63) / 64;   // 782

  // ---------------- layer 1: scores, input-space gather, GEMM -> hb -------
  rowdot6<<<AGG_G, B, 0, stream>>>(xb, wvec1, el, er);
  gat_gather_hl<<<AGG16, B, 0, stream>>>(row_ptr, csr_src, el, er, xb, A1);
  gemm_hl<<<GEMM_GX, B, 0, stream>>>(A1, W1d, beff1, hb, NN);

  // ---------------- layer 2: project, gather+dots -------------------------
  {
    dim3 g(GEMM_GX, NREL);
    gemm_fused2<<<g, B, 0, stream>>>(hb, W2t, al2, ar2, featb2, el, er, NN);
  }
  gat_agg_dots<<<AGG16, B, 0, stream>>>(row_ptr, csr_src, el, er, featb2,
                                        beff2, Wlin, dotl, dotr);

  // ---------------- pair predictor ----------------------------------------
  const int TOT = NREL * NE + NP;
  pair_out<<<(TOT + B - 1) / B, B, 0, stream>>>(edges, npairs, dotl, dotr, blin, out);
}

// Round 17
// 239.658 us; speedup vs baseline: 1.0644x; 1.0644x over previous
//
#include <hip/hip_runtime.h>
#include <cstddef>

#define NN 50000
#define NREL 3
#define NE 250000
#define NP 100000
#define FIN 128
#define HD 256
#define SLOPE 0.2f
#define K1 (NREL * FIN)          // 384

typedef short bf16x8 __attribute__((ext_vector_type(8)));
typedef short bf16x2 __attribute__((ext_vector_type(2)));
typedef float f32x4 __attribute__((ext_vector_type(4)));
typedef _Float16 half8 __attribute__((ext_vector_type(8)));

__device__ __forceinline__ short f2bf(float f) {
  unsigned u = __float_as_uint(f);
  unsigned r = (u + 0x7FFFu + ((u >> 16) & 1u)) >> 16;   // RNE
  return (short)r;
}
__device__ __forceinline__ float bf2f(short s) {
  return __uint_as_float(((unsigned)(unsigned short)s) << 16);
}

// async global->LDS, 16 bytes per lane; lds ptr must be wave-uniform base.
__device__ __forceinline__ void gload16(const short* g, short* l) {
  __builtin_amdgcn_global_load_lds(
      (const __attribute__((address_space(1))) unsigned int*)g,
      (__attribute__((address_space(3))) unsigned int*)l, 16, 0, 0);
}

// -------- fused prep + edge counting (rank capture) -----------------------
// ranges: [0,2930) count+rank | [2930,9180) xconv | [9180,9564) W1d f16
//         [9564,9948) W2t | [9948,10140) wvec1 | [10140,10142) beff
// swizzle: element (n,k) stored at k ^ ((n&7)<<3)  [within 64-short windows]
__global__ __launch_bounds__(256) void prep_all(
    const float* __restrict__ x,  const float* __restrict__ W1,
    const float* __restrict__ W2, const float* __restrict__ al1,
    const float* __restrict__ ar1, const float* __restrict__ b1,
    const float* __restrict__ b2,  const int* __restrict__ edges,
    int* __restrict__ deg, int* __restrict__ rank,
    short* __restrict__ xb, short* __restrict__ W1d, short* __restrict__ W2t,
    float* __restrict__ wvec1, float* __restrict__ beff1, float* __restrict__ beff2)
{
  const int blk = blockIdx.x;
  const int t = threadIdx.x;
  if (blk < 2930) {                                   // edge count + rank
    int tid2 = blk * 256 + t;
    if (tid2 < NREL * NE) {
      int r = tid2 / NE;
      int e = tid2 - r * NE;
      int d = edges[(size_t)r * 2 * NE + NE + e];
      rank[tid2] = atomicAdd(&deg[r * NN + d], 1);
    }
  } else if (blk < 9180) {                            // x -> bf16
    int i = ((blk - 2930) * 256 + t) * 4;
    float4 v = *(const float4*)&x[i];
    short4 o = {f2bf(v.x), f2bf(v.y), f2bf(v.z), f2bf(v.w)};
    *(short4*)&xb[i] = o;
  } else if (blk < 9564) {                            // W1d[n][kpos] f16, k<384
    int o = (blk - 9180) * 256 + t;
    int n = o / K1;
    int kpos = o - n * K1;
    int ke = kpos ^ ((n & 7) << 3);                   // element for this slot
    int r = ke / FIN, kk = ke - r * FIN;
    ((_Float16*)W1d)[o] = (_Float16)W1[((size_t)r * FIN + kk) * HD + n];
  } else if (blk < 9948) {                            // W2t[r][n][kpos] bf16
    int o = (blk - 9564) * 256 + t;
    int r = o / (FIN * HD);
    int rem = o - r * (FIN * HD);
    int n = rem / HD, kpos = rem - n * HD;
    int ke = kpos ^ ((n & 7) << 3);
    W2t[o] = f2bf(W2[((size_t)r * HD + ke) * FIN + n]);
  } else if (blk < 10140) {                           // wvec1[j][k] = W1_r[k,:]·v
    int wid = (blk - 9948) * 4 + (t >> 6);
    int lane = t & 63;
    if (wid < 6 * FIN) {
      int j = wid / FIN, k = wid - j * FIN;
      int side = j / 3, r = j - side * 3;
      const float* v  = (side ? ar1 : al1) + r * HD;
      const float* Wr = W1 + ((size_t)r * FIN + k) * HD;
      float s = 0.f;
      for (int n = lane; n < HD; n += 64) s += Wr[n] * v[n];
#pragma unroll
      for (int off = 32; off > 0; off >>= 1) s += __shfl_down(s, off);
      if (lane == 0) wvec1[wid] = s;
    }
  } else {                                            // beff
    int t2 = (blk - 10140) * 256 + t;
    if (t2 < HD) beff1[t2] = (b1[t2] + b1[HD + t2] + b1[2 * HD + t2]) * (1.f / 3.f);
    else if (t2 < HD + FIN) {
      int k = t2 - HD;
      beff2[k] = (b2[k] + b2[FIN + k] + b2[2 * FIN + k]) * (1.f / 3.f);
    }
  }
}

// ------- el/er for layer 1: d[j] = xb[i,:]·wvec1[j,:], j<6 ----------------
__global__ __launch_bounds__(256) void rowdot6(
    const short* __restrict__ feat, const float* __restrict__ wvec,
    float* __restrict__ el, float* __restrict__ er)
{
  const int lane = threadIdx.x & 63;
  const int node = blockIdx.x * 4 + (threadIdx.x >> 6);
  if (node >= NN) return;
  bf16x2 f16 = *(const bf16x2*)&feat[(size_t)node * FIN + lane * 2];
  float f0 = bf2f(f16[0]), f1 = bf2f(f16[1]);
  float d[6];
#pragma unroll
  for (int j = 0; j < 6; ++j)
    d[j] = f0 * wvec[j * FIN + lane * 2] + f1 * wvec[j * FIN + lane * 2 + 1];
#pragma unroll
  for (int off = 32; off > 0; off >>= 1)
#pragma unroll
    for (int j = 0; j < 6; ++j) d[j] += __shfl_xor(d[j], off);
  if (lane == 0) {
    el[0 * NN + node] = d[0]; el[1 * NN + node] = d[1]; el[2 * NN + node] = d[2];
    er[0 * NN + node] = d[3]; er[1 * NN + node] = d[4]; er[2 * NN + node] = d[5];
  }
}

// ------------- CSR scan phase 1 -------------------------------------------
__global__ __launch_bounds__(256) void deg_partial(
    const int* __restrict__ deg, int* __restrict__ psum)
{
  const int b = blockIdx.x;
  const int t = threadIdx.x;
  int4 v = {0, 0, 0, 0};
  if (t < 250) v = *(const int4*)&deg[b * 1000 + t * 4];
  int s = v.x + v.y + v.z + v.w;
#pragma unroll
  for (int off = 32; off > 0; off >>= 1) s += __shfl_down(s, off);
  __shared__ int ws[4];
  if ((t & 63) == 0) ws[t >> 6] = s;
  __syncthreads();
  if (t == 0) psum[b] = ws[0] + ws[1] + ws[2] + ws[3];
}

// ------------- CSR scan phase 2 -------------------------------------------
__global__ __launch_bounds__(256) void scan_psum(
    const int* __restrict__ psum, int* __restrict__ pexcl)
{
  __shared__ int lds[256];
  const int t = threadIdx.x;
  int v = (t < 150) ? psum[t] : 0;
  lds[t] = v;
  __syncthreads();
  for (int off = 1; off < 256; off <<= 1) {
    int add = (t >= off) ? lds[t - off] : 0;
    __syncthreads();
    lds[t] += add;
    __syncthreads();
  }
  if (t < 150) pexcl[t] = lds[t] - v;
}

// ------------- CSR scan phase 3: row_ptr --------------------------------
__global__ __launch_bounds__(256) void deg_rowptr(
    const int* __restrict__ deg, const int* __restrict__ pexcl,
    int* __restrict__ row_ptr)
{
  const int b = blockIdx.x;
  const int t = threadIdx.x;
  int4 v = {0, 0, 0, 0};
  if (t < 250) v = *(const int4*)&deg[b * 1000 + t * 4];
  int s = v.x + v.y + v.z + v.w;
  __shared__ int lds[256];
  lds[t] = s;
  __syncthreads();
  for (int off = 1; off < 256; off <<= 1) {
    int add = (t >= off) ? lds[t - off] : 0;
    __syncthreads();
    lds[t] += add;
    __syncthreads();
  }
  int run = lds[t] - s + pexcl[b];
  if (t < 250) {
    int i = b * 1000 + t * 4;
    row_ptr[i] = run;     run += v.x;
    row_ptr[i + 1] = run; run += v.y;
    row_ptr[i + 2] = run; run += v.z;
    row_ptr[i + 3] = run;
  }
  if (b == 0 && t == 0) row_ptr[NREL * NN] = NREL * NE;
}

// ------------- CSR fill: atomic-free (uses captured rank) -----------------
__global__ __launch_bounds__(256) void fill_csr(
    const int* __restrict__ edges, const int* __restrict__ row_ptr,
    const int* __restrict__ rank, int* __restrict__ csr_src)
{
  int tid = blockIdx.x * blockDim.x + threadIdx.x;
  if (tid >= NREL * NE) return;
  int r = tid / NE;
  int e = tid - r * NE;
  const int* base = edges + (size_t)r * 2 * NE;
  int s = base[e];
  int d = base[NE + e];
  csr_src[row_ptr[r * NN + d] + rank[tid]] = s;
}

// ------------- canonicalize bucket order: sort each bucket by src ---------
// LDS working set (rule #20: runtime-indexed register arrays spill to
// scratch; LDS [i][tid] layout = 1 bank/lane, 2-way aliasing = free).
__global__ __launch_bounds__(256) void sort_csr(
    const int* __restrict__ row_ptr, int* __restrict__ csr_src)
{
  __shared__ int buf[24][256];
  const int t = threadIdx.x;
  int b = blockIdx.x * 256 + t;
  if (b >= NREL * NN) return;
  const int beg = row_ptr[b];
  const int end = row_ptr[b + 1];
  const int n = end - beg;
  if (n <= 1) return;
  if (n <= 24) {
    for (int i = 0; i < n; ++i) buf[i][t] = csr_src[beg + i];
    for (int i = 1; i < n; ++i) {
      int key = buf[i][t];
      int j = i - 1;
      while (j >= 0 && buf[j][t] > key) { buf[j + 1][t] = buf[j][t]; --j; }
      buf[j + 1][t] = key;
    }
    for (int i = 0; i < n; ++i) csr_src[beg + i] = buf[i][t];
  } else {                               // rare (P~1e-10): deterministic
    for (int i = beg; i < end - 1; ++i) {
      int mi = i;
      for (int j = i + 1; j < end; ++j)
        if (csr_src[j] < csr_src[mi]) mi = j;
      int tmp = csr_src[mi]; csr_src[mi] = csr_src[i]; csr_src[i] = tmp;
    }
  }
}

// ------- L1: input-space fused 3-relation gather, 16 lanes per node -------
// 4 nodes/wave; each lane owns 8 channels. A1 written as fp16, PRE-SWIZZLED:
// element (node,k) at k ^ ((node&7)<<3).
__global__ __launch_bounds__(256) void gat_gather_hl(
    const int* __restrict__ row_ptr, const int* __restrict__ csr_src,
    const float* __restrict__ el, const float* __restrict__ er,
    const short* __restrict__ xb,       // [NN][FIN] bf16
    short* __restrict__ A1)             // [NN][384] f16, swizzled
{
  const int lane  = threadIdx.x & 63;
  const int cl    = lane & 15;
  const int gbase = lane & 48;
  const int node  = blockIdx.x * 16 + (threadIdx.x >> 6) * 4 + (lane >> 4);
  if (node >= NN) return;
  const int sw = (node & 7) << 3;
  const size_t rowbase = (size_t)node * K1;

#pragma unroll
  for (int r = 0; r < NREL; ++r) {
    const int beg = row_ptr[r * NN + node];
    const int end = row_ptr[r * NN + node + 1];
    const float eri = er[r * NN + node];
    const float* elr = el + r * NN;

    float dsum = 0.f;
    float f[8];
#pragma unroll
    for (int k = 0; k < 8; ++k) f[k] = 0.f;

    for (int chunk = beg; chunk < end; chunk += 16) {
      int e = chunk + cl;
      int sidx = 0; float a = 0.f;
      if (e < end) {
        sidx = csr_src[e];
        float tv = elr[sidx] + eri;
        tv = tv > 0.f ? tv : SLOPE * tv;
        a = __expf(tv);
      }
      dsum += a;
      const int cnt = (end - chunk < 16) ? end - chunk : 16;
      for (int i = 0; i < cnt; ++i) {
        float aj = __shfl(a, gbase + i);
        int   sj = __shfl(sidx, gbase + i);
        bf16x8 v = *(const bf16x8*)&xb[(size_t)sj * FIN + cl * 8];
#pragma unroll
        for (int k = 0; k < 8; ++k) f[k] = fmaf(bf2f(v[k]), aj, f[k]);
      }
    }
#pragma unroll
    for (int off = 8; off > 0; off >>= 1) dsum += __shfl_xor(dsum, off);
    const float inv = 1.f / (3.f * fmaxf(dsum, 1e-9f));

    half8 hv;
#pragma unroll
    for (int k = 0; k < 8; ++k) hv[k] = (_Float16)(f[k] * inv);
    int u = (r * FIN + cl * 8) ^ sw;       // swizzled within 64-short window
    *(half8*)&A1[rowbase + u] = hv;
  }
}

// ------- L1 GEMM: hb = relu(A1@W1d^T + beff1), f16 MFMA, A read ONCE ------
// BM=64, BN=256 (full width, wave=64 cols), BK=64, K=384. LDS 40 KB.
__global__ __launch_bounds__(256) void gemm_hl(
    const short* __restrict__ A, const short* __restrict__ Bt,
    const float* __restrict__ beff, short* __restrict__ hb, int M)
{
  constexpr int BK = 64;
  __shared__ __align__(16) short AsB[(64 + 256) * BK];  // 40 KB
  short* As = AsB;
  short* Bs = AsB + 64 * BK;
  const int tid  = threadIdx.x;
  const int lane = tid & 63;
  const int wave = tid >> 6;
  const int m0 = blockIdx.x * 64;
  const int n0 = wave * 64;
  const int c    = lane & 15;
  const int rgrp = lane >> 4;
  const int wbase = tid & ~63;         // wave-uniform chunk base

  f32x4 acc[4][4] = {};
  for (int k0 = 0; k0 < K1; k0 += BK) {
    __syncthreads();
#pragma unroll
    for (int q = 0; q < 2; ++q) {      // A: 512 chunks
      int idx = q * 256 + tid;
      int row = idx >> 3, ch = idx & 7;
      int gr = m0 + row; gr = gr < M ? gr : M - 1;
      gload16(&A[(size_t)gr * K1 + k0 + ch * 8], As + (q * 256 + wbase) * 8);
    }
#pragma unroll
    for (int q = 0; q < 8; ++q) {      // B: 2048 chunks (256 cols)
      int jdx = q * 256 + tid;
      int col = jdx >> 3, ch = jdx & 7;
      gload16(&Bt[(size_t)col * K1 + k0 + ch * 8], Bs + (q * 256 + wbase) * 8);
    }
    __syncthreads();
#pragma unroll
    for (int ks = 0; ks < 2; ++ks) {
      const int ko = (ks * 32 + rgrp * 8) ^ ((c & 7) << 3);  // de-swizzle
      half8 a[4], b[4];
#pragma unroll
      for (int i = 0; i < 4; ++i)
        a[i] = *(const half8*)&As[(i * 16 + c) * BK + ko];
#pragma unroll
      for (int j = 0; j < 4; ++j)
        b[j] = *(const half8*)&Bs[(n0 + j * 16 + c) * BK + ko];
#pragma unroll
      for (int i = 0; i < 4; ++i)
#pragma unroll
        for (int j = 0; j < 4; ++j)
          acc[i][j] = __builtin_amdgcn_mfma_f32_16x16x32_f16(a[i], b[j], acc[i][j], 0, 0, 0);
    }
  }
#pragma unroll
  for (int i = 0; i < 4; ++i)
#pragma unroll
    for (int v = 0; v < 4; ++v) {
      int row = m0 + i * 16 + rgrp * 4 + v;
      if (row < M) {
        int srow = (row & 7) << 3;
#pragma unroll
        for (int j = 0; j < 4; ++j) {
          int col = n0 + j * 16 + c;
          hb[(size_t)row * HD + (col ^ srow)] =
              f2bf(fmaxf(acc[i][j][v] + beff[col], 0.f));
        }
      }
    }
}

// ---- L2 GEMM: featb[r] = hb @ W2t[r]^T + el/er epilogue (bf16 MFMA) ------
// BM=64, BN=128 (full N), BK=64, grid y=3. hb/W2t are pre-swizzled.
__global__ __launch_bounds__(256) void gemm_fused2(
    const short* __restrict__ A, const short* __restrict__ Wt,
    const float* __restrict__ al, const float* __restrict__ ar,
    short* __restrict__ featb, float* __restrict__ el, float* __restrict__ er,
    int M)
{
  constexpr int K = HD;                // 256
  constexpr int BK = 64;
  constexpr int N_ = FIN;              // 128
  __shared__ __align__(16) short AsB[(64 + 128) * BK];  // 24 KB
  __shared__ float2 part[4][64];
  short* As = AsB;
  short* Bs = AsB + 64 * BK;
  const int r = blockIdx.y;
  const short* Bt  = Wt + (size_t)r * N_ * K;
  const float* alr = al + r * N_;
  const float* arr = ar + r * N_;
  short* fb  = featb + (size_t)r * M * N_;
  float* elr = el + r * NN;
  float* err = er + r * NN;

  const int tid  = threadIdx.x;
  const int lane = tid & 63;
  const int wave = tid >> 6;
  const int m0 = blockIdx.x * 64;
  const int c    = lane & 15;
  const int rgrp = lane >> 4;
  const int wbase = tid & ~63;

  f32x4 acc[4][2] = {};
  for (int k0 = 0; k0 < K; k0 += BK) {
    __syncthreads();
#pragma unroll
    for (int q = 0; q < 2; ++q) {
      int idx = q * 256 + tid;
      int row = idx >> 3, ch = idx & 7;
      int gr = m0 + row; gr = gr < M ? gr : M - 1;
      gload16(&A[(size_t)gr * K + k0 + ch * 8], As + (q * 256 + wbase) * 8);
    }
#pragma unroll
    for (int q = 0; q < 4; ++q) {
      int jdx = q * 256 + tid;
      int col = jdx >> 3, ch = jdx & 7;
      gload16(&Bt[(size_t)col * K + k0 + ch * 8], Bs + (q * 256 + wbase) * 8);
    }
    __syncthreads();
#pragma unroll
    for (int ks = 0; ks < 2; ++ks) {
      const int ko = (ks * 32 + rgrp * 8) ^ ((c & 7) << 3);
      bf16x8 a[4], b[2];
#pragma unroll
      for (int i = 0; i < 4; ++i)
        a[i] = *(const bf16x8*)&As[(i * 16 + c) * BK + ko];
#pragma unroll
      for (int j = 0; j < 2; ++j)
        b[j] = *(const bf16x8*)&Bs[(wave * 32 + j * 16 + c) * BK + ko];
#pragma unroll
      for (int i = 0; i < 4; ++i)
#pragma unroll
        for (int j = 0; j < 2; ++j)
          acc[i][j] = __builtin_amdgcn_mfma_f32_16x16x32_bf16(a[i], b[j], acc[i][j], 0, 0, 0);
    }
  }

  // epilogue: featb (bf16, normal layout) + el/er dots
  float pe[4][4], pr[4][4];
#pragma unroll
  for (int i = 0; i < 4; ++i)
#pragma unroll
    for (int v = 0; v < 4; ++v) {
      float se = 0.f, sr = 0.f;
#pragma unroll
      for (int j = 0; j < 2; ++j) {
        float av = acc[i][j][v];
        int col = wave * 32 + j * 16 + c;
        se = fmaf(av, alr[col], se);
        sr = fmaf(av, arr[col], sr);
      }
      pe[i][v] = se; pr[i][v] = sr;
    }
#pragma unroll
  for (int i = 0; i < 4; ++i)
#pragma unroll
    for (int v = 0; v < 4; ++v) {
      int row = m0 + i * 16 + rgrp * 4 + v;
      if (row < M) {
#pragma unroll
        for (int j = 0; j < 2; ++j)
          fb[(size_t)row * N_ + wave * 32 + j * 16 + c] = f2bf(acc[i][j][v]);
      }
#pragma unroll
      for (int off = 1; off < 16; off <<= 1) {
        pe[i][v] += __shfl_xor(pe[i][v], off);
        pr[i][v] += __shfl_xor(pr[i][v], off);
      }
    }
  if (c == 0) {
#pragma unroll
    for (int i = 0; i < 4; ++i)
#pragma unroll
      for (int v = 0; v < 4; ++v)
        part[wave][i * 16 + rgrp * 4 + v] = make_float2(pe[i][v], pr[i][v]);
  }
  __syncthreads();
  if (tid < 64) {
    float se = 0.f, sr = 0.f;
#pragma unroll
    for (int w = 0; w < 4; ++w) { se += part[w][tid].x; sr += part[w][tid].y; }
    int row = m0 + tid;
    if (row < M) { elr[row] = se; err[row] = sr; }
  }
}

// ---- L2: projected-space gather + relu + predictor dots, 16 lanes/node ---
__global__ __launch_bounds__(256) void gat_agg_dots(
    const int* __restrict__ row_ptr, const int* __restrict__ csr_src,
    const float* __restrict__ el, const float* __restrict__ er,
    const short* __restrict__ featb,    // [NREL][NN][FIN] bf16 (normal layout)
    const float* __restrict__ beff,     // [FIN]
    const float* __restrict__ Wlin,     // [2*FIN]
    float* __restrict__ dotl, float* __restrict__ dotr)
{
  const int lane  = threadIdx.x & 63;
  const int cl    = lane & 15;
  const int gbase = lane & 48;
  const int node  = blockIdx.x * 16 + (threadIdx.x >> 6) * 4 + (lane >> 4);
  if (node >= NN) return;

  float t[8];
#pragma unroll
  for (int k = 0; k < 8; ++k) t[k] = 0.f;

#pragma unroll
  for (int r = 0; r < NREL; ++r) {
    const int beg = row_ptr[r * NN + node];
    const int end = row_ptr[r * NN + node + 1];
    const float eri = er[r * NN + node];
    const float* elr = el + r * NN;
    const short* fb  = featb + (size_t)r * NN * FIN;

    float dsum = 0.f;
    float f[8];
#pragma unroll
    for (int k = 0; k < 8; ++k) f[k] = 0.f;

    for (int chunk = beg; chunk < end; chunk += 16) {
      int e = chunk + cl;
      int sidx = 0; float a = 0.f;
      if (e < end) {
        sidx = csr_src[e];
        float tv = elr[sidx] + eri;
        tv = tv > 0.f ? tv : SLOPE * tv;
        a = __expf(tv);
      }
      dsum += a;
      const int cnt = (end - chunk < 16) ? end - chunk : 16;
      for (int i = 0; i < cnt; ++i) {
        float aj = __shfl(a, gbase + i);
        int   sj = __shfl(sidx, gbase + i);
        bf16x8 v = *(const bf16x8*)&fb[(size_t)sj * FIN + cl * 8];
#pragma unroll
        for (int k = 0; k < 8; ++k) f[k] = fmaf(bf2f(v[k]), aj, f[k]);
      }
    }
#pragma unroll
    for (int off = 8; off > 0; off >>= 1) dsum += __shfl_xor(dsum, off);
    const float inv = 1.f / (3.f * fmaxf(dsum, 1e-9f));
#pragma unroll
    for (int k = 0; k < 8; ++k) t[k] = fmaf(f[k], inv, t[k]);
  }

  const int c = cl * 8;
  float dl = 0.f, dr = 0.f;
#pragma unroll
  for (int k = 0; k < 8; ++k) {
    float g = fmaxf(t[k] + beff[c + k], 0.f);
    dl = fmaf(g, Wlin[c + k], dl);
    dr = fmaf(g, Wlin[FIN + c + k], dr);
  }
#pragma unroll
  for (int off = 8; off > 0; off >>= 1) {
    dl += __shfl_xor(dl, off);
    dr += __shfl_xor(dr, off);
  }
  if (cl == 0) { dotl[node] = dl; dotr[node] = dr; }
}

// ------------- pair logits -------------------------------------------------
__global__ __launch_bounds__(256) void pair_out(
    const int* __restrict__ edges, const int* __restrict__ n_pairs,
    const float* __restrict__ dotl, const float* __restrict__ dotr,
    const float* __restrict__ blin, float* __restrict__ out)
{
  const int TOT = NREL * NE + NP;
  int p = blockIdx.x * blockDim.x + threadIdx.x;
  if (p >= TOT) return;
  int s, d;
  if (p < NREL * NE) {
    int r = p / NE;
    int e = p - r * NE;
    const int* base = edges + (size_t)r * 2 * NE;
    s = base[e];
    d = base[NE + e];
  } else {
    int q = p - NREL * NE;
    s = n_pairs[2 * q];
    d = n_pairs[2 * q + 1];
  }
  float logit = dotl[s] + dotr[d] + blin[0];
  out[p] = 1.f / (1.f + expf(-logit));
}

extern "C" void kernel_launch(void* const* d_in, const int* in_sizes, int n_in,
                              void* d_out, int out_size, void* d_ws, size_t ws_size,
                              hipStream_t stream) {
  const float* x      = (const float*)d_in[0];
  const int*   edges  = (const int*)d_in[1];
  const int*   npairs = (const int*)d_in[2];
  const float* W1     = (const float*)d_in[3];
  const float* al1    = (const float*)d_in[4];
  const float* ar1    = (const float*)d_in[5];
  const float* b1     = (const float*)d_in[6];
  const float* W2     = (const float*)d_in[7];
  const float* al2    = (const float*)d_in[8];
  const float* ar2    = (const float*)d_in[9];
  const float* b2     = (const float*)d_in[10];
  const float* Wlin   = (const float*)d_in[11];
  const float* blin   = (const float*)d_in[12];
  float* out = (float*)d_out;

  char* w = (char*)d_ws;
  size_t off = 0;
  auto alloc = [&](size_t bytes) {
    char* p = w + off;
    off = (off + bytes + 255) & ~(size_t)255;
    return p;
  };
  short* xb      = (short*)alloc((size_t)NN * FIN * 2);     // 12.8 MB
  short* hb      = (short*)alloc((size_t)NN * HD * 2);      // 25.6 MB
  short* A1      = (short*)alloc((size_t)NN * K1 * 2);      // 38.4 MB (f16)
  short* featb2  = A1;   // aliased: A1 dead after gemm_hl (needs 38.4 MB)
  short* W1d     = (short*)alloc((size_t)HD * K1 * 2);      // 196 KB (f16)
  short* W2t     = (short*)alloc((size_t)NREL * FIN * HD * 2);
  float* wvec1   = (float*)alloc(6 * FIN * 4);
  float* beff1   = (float*)alloc(HD * 4);
  float* beff2   = (float*)alloc(FIN * 4);
  float* el      = (float*)alloc((size_t)NREL * NN * 4);
  float* er      = (float*)alloc((size_t)NREL * NN * 4);
  float* dotl    = (float*)alloc((size_t)NN * 4);
  float* dotr    = (float*)alloc((size_t)NN * 4);
  int*   deg     = (int*)  alloc((size_t)NREL * NN * 4);
  int*   rank    = (int*)  alloc((size_t)NREL * NE * 4);    // 3 MB
  int*   row_ptr = (int*)  alloc((size_t)(NREL * NN + 16) * 4);
  int*   psum    = (int*)  alloc(1024);
  int*   pexcl   = (int*)  alloc(1024);
  int*   csr_src = (int*)  alloc((size_t)NREL * NE * 4);

  const int B = 256;

  // ---------------- prep + edge count (1 kernel) --------------------------
  hipMemsetAsync(deg, 0, (size_t)NREL * NN * 4, stream);
  prep_all<<<10142, B, 0, stream>>>(x, W1, W2, al1, ar1, b1, b2, edges,
                                    deg, rank, xb, W1d, W2t, wvec1, beff1, beff2);

  // ---------------- CSR scan + atomic-free fill + canonical sort ----------
  deg_partial<<<150, B, 0, stream>>>(deg, psum);
  scan_psum<<<1, B, 0, stream>>>(psum, pexcl);
  deg_rowptr<<<150, B, 0, stream>>>(deg, pexcl, row_ptr);
  fill_csr<<<(NREL * NE + B - 1) / B, B, 0, stream>>>(edges, row_ptr, rank, csr_src);
  sort_csr<<<(NREL * NN + B - 1) / B, B, 0, stream>>>(row_ptr, csr_src);

  const int AGG_G  = (NN + 3) / 4;
  const int AGG16  = (NN + 15) / 16;    // 3125
  const int GEMM_GX = (NN + 63) / 64;   // 782

  // ---------------- layer 1: scores, input-space gather, GEMM -> hb -------
  rowdot6<<<AGG_G, B, 0, stream>>>(xb, wvec1, el, er);
  gat_gather_hl<<<AGG16, B, 0, stream>>>(row_ptr, csr_src, el, er, xb, A1);
  gemm_hl<<<GEMM_GX, B, 0, stream>>>(A1, W1d, beff1, hb, NN);

  // ---------------- layer 2: project, gather+dots -------------------------
  {
    dim3 g(GEMM_GX, NREL);
    gemm_fused2<<<g, B, 0, stream>>>(hb, W2t, al2, ar2, featb2, el, er, NN);
  }
  gat_agg_dots<<<AGG16, B, 0, stream>>>(row_ptr, csr_src, el, er, featb2,
                                        beff2, Wlin, dotl, dotr);

  // ---------------- pair predictor ----------------------------------------
  const int TOT = NREL * NE + NP;
  pair_out<<<(TOT + B - 1) / B, B, 0, stream>>>(edges, npairs, dotl, dotr, blin, out);
}